// Round 6
// baseline (200.309 us; speedup 1.0000x reference)
//
#include <hip/hip_runtime.h>
#include <hip/hip_bf16.h>

// SimCSE loss: loss = mean_i( logsumexp_j(sim[i][j]) - sim[i][i] ),
// sim = normalize(q) @ normalize(c)^T / 0.05.  N=8192, D=768, fp32 in, scalar out.
//
// GEMM: 256x256 tiles, 8 waves (2Mx4N), BK=64, 128KiB LDS dbuf + 4KB red slice.
// Round-6: PERSISTENT FLAT PIPELINE — 256 blocks, each runs 4 tiles (same tm)
// as one continuous 24-iteration K-stream; staging wraps across tile
// boundaries so the vmcnt(6) lookahead never drains. Per-tile epilogue uses a
// dedicated LDS slice + raw barriers + lgkm-only waits (staging stays in
// flight). ds_reads ordered B-then-A to match MFMA consumption for partial
// lgkm overlap.

#define NROWS 8192
#define DDIM  768
#define ROWB  1536              // bytes per bf16 row
#define PANEL (256 * ROWB)      // bytes per 256-row tile panel
#define GRID_T (NROWS / 256)    // 32 tiles per dim
#define NTILE 4                 // tiles per block
#define NITT  24                // 6 K-iters per tile * 4 tiles

constexpr float INV_TEMP = 20.0f;   // 1/0.05
constexpr float NORM_EPS = 1e-8f;

using bf16 = __hip_bfloat16;
typedef __attribute__((ext_vector_type(4))) float  f32x4;
typedef __attribute__((ext_vector_type(8))) short  bf16x8;

// ---------------------------------------------------------------- fused normalize + diag
__global__ void norm_diag_kernel(const float* __restrict__ q, const float* __restrict__ c,
                                 bf16* __restrict__ qn, bf16* __restrict__ cn,
                                 float* __restrict__ diag) {
    const int row  = (blockIdx.x * 256 + threadIdx.x) >> 6;
    const int lane = threadIdx.x & 63;
    const float4* qv = (const float4*)(q + (size_t)row * DDIM);
    const float4* cv = (const float4*)(c + (size_t)row * DDIM);
    float4 a[3], b[3];
    #pragma unroll
    for (int j = 0; j < 3; ++j) { a[j] = qv[lane + j * 64]; b[j] = cv[lane + j * 64]; }
    float ssq = 0.f, ssc = 0.f, dot = 0.f;
    #pragma unroll
    for (int j = 0; j < 3; ++j) {
        ssq += a[j].x * a[j].x + a[j].y * a[j].y + a[j].z * a[j].z + a[j].w * a[j].w;
        ssc += b[j].x * b[j].x + b[j].y * b[j].y + b[j].z * b[j].z + b[j].w * b[j].w;
        dot += a[j].x * b[j].x + a[j].y * b[j].y + a[j].z * b[j].z + a[j].w * b[j].w;
    }
    #pragma unroll
    for (int m = 32; m; m >>= 1) {
        ssq += __shfl_xor(ssq, m);
        ssc += __shfl_xor(ssc, m);
        dot += __shfl_xor(dot, m);
    }
    float invq = 1.0f / fmaxf(sqrtf(ssq), NORM_EPS);
    float invc = 1.0f / fmaxf(sqrtf(ssc), NORM_EPS);
    if (lane == 0) diag[row] = dot * invq * invc * INV_TEMP;
    ushort4* qo = (ushort4*)(qn + (size_t)row * DDIM);
    ushort4* co = (ushort4*)(cn + (size_t)row * DDIM);
    #pragma unroll
    for (int j = 0; j < 3; ++j) {
        union { ushort4 u; bf16 h[4]; } oq, oc;
        oq.h[0] = __float2bfloat16(a[j].x * invq); oq.h[1] = __float2bfloat16(a[j].y * invq);
        oq.h[2] = __float2bfloat16(a[j].z * invq); oq.h[3] = __float2bfloat16(a[j].w * invq);
        oc.h[0] = __float2bfloat16(b[j].x * invc); oc.h[1] = __float2bfloat16(b[j].y * invc);
        oc.h[2] = __float2bfloat16(b[j].z * invc); oc.h[3] = __float2bfloat16(b[j].w * invc);
        qo[lane + j * 64] = oq.u;
        co[lane + j * 64] = oc.u;
    }
}

// ---------------------------------------------------------------- GEMM + expsum
__device__ __forceinline__ void async16(void* l, const void* g) {
    __builtin_amdgcn_global_load_lds(
        (const __attribute__((address_space(1))) void*)g,
        (__attribute__((address_space(3))) void*)l, 16, 0, 0);
}

#define BARRIER __builtin_amdgcn_s_barrier()
#define SCHED0  __builtin_amdgcn_sched_barrier(0)
#define PRIO1   __builtin_amdgcn_s_setprio(1)
#define PRIO0   __builtin_amdgcn_s_setprio(0)
#define VMCNT(n) do { asm volatile("s_waitcnt vmcnt(" #n ")" ::: "memory"); } while (0)
#define LGKM0   do { asm volatile("s_waitcnt lgkmcnt(0)" ::: "memory"); SCHED0; } while (0)

// LDS map (bytes): parity p: A at p*65536, B at 32768 + p*65536; half h at
// +h*16384. red[] slice at 131072 (4KB). Stage one half-tile = 2 loads/thread.
#define STAGE_A(P, H, K) do {                                               \
    const char* _g = aG + (size_t)(H) * 128 * ROWB + (size_t)(K) * 128;     \
    char* _l = lds + (P) * 65536 + (H) * 16384 + dstW;                      \
    async16(_l, _g);                                                        \
    async16(_l + 8192, _g + 64 * ROWB);                                     \
} while (0)
#define STAGE_B(P, H, BP, K) do {                                           \
    const char* _g = (BP) + (size_t)(H) * 128 * ROWB + (size_t)(K) * 128;   \
    char* _l = lds + 32768 + (P) * 65536 + (H) * 16384 + dstW;              \
    async16(_l, _g);                                                        \
    async16(_l + 8192, _g + 64 * ROWB);                                     \
} while (0)

#define READ_A(P, MH) do {                                                  \
    const char* _ab = lds + (P) * 65536 + aBaseT + (MH) * 64 * 128;         \
    _Pragma("unroll") for (int mi = 0; mi < 4; ++mi) {                      \
        a[mi][0] = *(const bf16x8*)(_ab + mi * 2048 + xk0);                 \
        a[mi][1] = *(const bf16x8*)(_ab + mi * 2048 + xk1);                 \
    }                                                                       \
} while (0)
#define READ_B(P, NH) do {                                                  \
    const char* _bb = lds + 32768 + (P) * 65536 + bBaseT + (NH) * 32 * 128; \
    _Pragma("unroll") for (int ni = 0; ni < 2; ++ni) {                      \
        bfr[NH][ni][0] = *(const bf16x8*)(_bb + ni * 2048 + xk0);           \
        bfr[NH][ni][1] = *(const bf16x8*)(_bb + ni * 2048 + xk1);           \
    }                                                                       \
} while (0)

#define MFMA_Q(MH, NH)                                                      \
    _Pragma("unroll") for (int mi = 0; mi < 4; ++mi)                        \
    _Pragma("unroll") for (int ni = 0; ni < 2; ++ni) {                      \
        acc[(MH)*4+mi][(NH)*2+ni] = __builtin_amdgcn_mfma_f32_16x16x32_bf16(\
            a[mi][0], bfr[NH][ni][0], acc[(MH)*4+mi][(NH)*2+ni], 0, 0, 0);  \
        acc[(MH)*4+mi][(NH)*2+ni] = __builtin_amdgcn_mfma_f32_16x16x32_bf16(\
            a[mi][1], bfr[NH][ni][1], acc[(MH)*4+mi][(NH)*2+ni], 0, 0, 0);  \
    }

__launch_bounds__(512, 2)
__global__ void simgemm_kernel(const bf16* __restrict__ A, const bf16* __restrict__ B,
                               float* __restrict__ partial) {
    __shared__ __attribute__((aligned(16))) char smem[131072 + 4096];
    char* lds = smem;

    // 256 blocks: tm = bid>>3 (A panel fixed), tn = tn0..tn0+3 over 4 tiles.
    const int bid = blockIdx.x;
    const int tm = bid >> 3;
    int tn = (bid & 7) * 4;
    const int rowBase = tm * 256;
    const int tid = threadIdx.x;
    const int wid = tid >> 6, lane = tid & 63;
    const int wr = wid >> 2, wc = wid & 3;

    // staging source (pre-swizzled involution; read side applies same XOR)
    const int sr  = tid >> 3;
    const int scb = ((tid & 7) * 16) ^ ((sr & 7) << 4);
    const char* aG = (const char*)A + (size_t)(rowBase + sr) * ROWB + scb;
    const char* bG = (const char*)B + (size_t)(tn * 256 + sr) * ROWB + scb;
    const int dstW = wid * 1024;

    const int aBaseT = wr * 16384 + (lane & 15) * 128;
    const int bBaseT = (wc >> 1) * 16384 + ((wc & 1) * 64 + (lane & 15)) * 128;
    const int klane  = (lane >> 4) * 16;
    const int swzr   = (lane & 7) << 4;
    const int xk0    = klane ^ swzr;
    const int xk1    = (64 + klane) ^ swzr;

    f32x4  acc[8][4] = {};
    bf16x8 a[4][2];
    bf16x8 bfr[2][2][2];

    // lookahead stage state: stage index T -> (kt = T%12, B panel ptr).
    // k1/b1 track T=2i+1, k2/b2 track T=2i+2, k3/b3 track T=2i+3.
    int k1 = 1, k2 = 2, k3 = 3;
    const char *b1 = bG, *b2 = bG, *b3 = bG;
    int ec = 0;                      // epilogue counter (6 iters per tile)

    // ---- prologue: stage T=0 fully (buf0) + T=1 A halves (buf1)
    STAGE_A(0, 0, 0); STAGE_A(0, 1, 0);
    STAGE_B(0, 0, bG, 0); STAGE_B(0, 1, bG, 0);
    STAGE_A(1, 0, 1); STAGE_A(1, 1, 1);
    VMCNT(4);          // T0 landed; T1.A (4 loads) in flight
    BARRIER; SCHED0;
    READ_B(0, 0); READ_A(0, 0);
    SCHED0;

    #pragma unroll 1
    for (int ii = 0; ii < NITT; ++ii) {
        const bool more = (ii + 1 < NITT);
        // ph1: MFMA even(0,0); stage B(t1,h0)
        STAGE_B(1, 0, b1, k1);
        PRIO1; MFMA_Q(0, 0); PRIO0;
        VMCNT(6);
        BARRIER; SCHED0;
        READ_B(0, 1); SCHED0;
        // ph2: MFMA(0,1); stage B(t1,h1)
        STAGE_B(1, 1, b1, k1);
        PRIO1; MFMA_Q(0, 1); PRIO0;
        BARRIER; SCHED0;
        READ_A(0, 1); SCHED0;
        // ph3: MFMA(1,0); stage A(t2,h0)
        if (more) STAGE_A(0, 0, k2);
        PRIO1; MFMA_Q(1, 0); PRIO0;
        BARRIER; SCHED0;
        // ph4: MFMA(1,1); stage A(t2,h1); ensure t1 landed for ph5-8 reads
        if (more) STAGE_A(0, 1, k2);
        PRIO1; MFMA_Q(1, 1); PRIO0;
        if (more) { VMCNT(6); } else { VMCNT(0); }
        BARRIER; SCHED0;
        READ_B(1, 0); READ_A(1, 0); SCHED0;
        // ph5: MFMA odd(0,0); stage B(t2,h0)
        if (more) STAGE_B(0, 0, b2, k2);
        PRIO1; MFMA_Q(0, 0); PRIO0;
        if (more) { VMCNT(6); }
        BARRIER; SCHED0;
        READ_B(1, 1); SCHED0;
        // ph6: MFMA(0,1); stage B(t2,h1)
        if (more) STAGE_B(0, 1, b2, k2);
        PRIO1; MFMA_Q(0, 1); PRIO0;
        BARRIER; SCHED0;
        READ_A(1, 1); SCHED0;
        // ph7: MFMA(1,0); stage A(t3,h0)
        if (more) STAGE_A(1, 0, k3);
        PRIO1; MFMA_Q(1, 0); PRIO0;
        BARRIER; SCHED0;
        // ph8: MFMA(1,1); stage A(t3,h1); ensure t2 landed for next reads
        if (more) STAGE_A(1, 1, k3);
        PRIO1; MFMA_Q(1, 1); PRIO0;
        if (more) { VMCNT(6); }
        BARRIER; SCHED0;
        if (more) { READ_B(0, 0); READ_A(0, 0); SCHED0; }

        // advance lookahead stage state (wrap across tile panels)
        k1 += 2; if (k1 >= 12) { k1 -= 12; b1 += PANEL; }
        k2 += 2; if (k2 >= 12) { k2 -= 12; b2 += PANEL; }
        k3 += 2; if (k3 >= 12) { k3 -= 12; b3 += PANEL; }

        // ---- per-tile epilogue every 6 iterations (staging stays in flight;
        // raw barriers + lgkm-only waits — no vmcnt drain)
        if (++ec == 6) {
            ec = 0;
            float* red = (float*)(lds + 131072);   // dedicated [256][4] slice
            #pragma unroll
            for (int m = 0; m < 8; ++m) {
                #pragma unroll
                for (int r = 0; r < 4; ++r) {
                    float s = 0.f;
                    #pragma unroll
                    for (int n = 0; n < 4; ++n)
                        s += __expf(fmaf(INV_TEMP, acc[m][n][r], -INV_TEMP));
                    s += __shfl_xor(s, 1);
                    s += __shfl_xor(s, 2);
                    s += __shfl_xor(s, 4);
                    s += __shfl_xor(s, 8);
                    if ((lane & 15) == 0)
                        red[(wr * 128 + m * 16 + (lane >> 4) * 4 + r) * 4 + wc] = s;
                }
            }
            LGKM0;            // red writes visible (does not wait vmcnt)
            BARRIER; SCHED0;
            if (tid < 256)
                partial[(size_t)(rowBase + tid) * GRID_T + tn] =
                    red[tid * 4 + 0] + red[tid * 4 + 1] +
                    red[tid * 4 + 2] + red[tid * 4 + 3];
            ++tn;
            #pragma unroll
            for (int m = 0; m < 8; ++m)
                #pragma unroll
                for (int n = 0; n < 4; ++n)
                    acc[m][n] = (f32x4){0.f, 0.f, 0.f, 0.f};
            BARRIER; SCHED0;  // red reads done before any future rewrite
        }
    }
}

// ---------------------------------------------------------------- finalize
__global__ void finalize_kernel(const float* __restrict__ partial,
                                const float* __restrict__ diag,
                                float* __restrict__ out) {
    int row = blockIdx.x * 256 + threadIdx.x;
    const float4* p = (const float4*)(partial + (size_t)row * GRID_T);
    float z = 0.f;
    #pragma unroll
    for (int i = 0; i < GRID_T / 4; ++i) {
        float4 v = p[i];
        z += v.x + v.y + v.z + v.w;
    }
    float term = INV_TEMP + logf(z) - diag[row];
    #pragma unroll
    for (int m = 32; m; m >>= 1) term += __shfl_xor(term, m);
    __shared__ float wsum[4];
    if ((threadIdx.x & 63) == 0) wsum[threadIdx.x >> 6] = term;
    __syncthreads();
    if (threadIdx.x == 0) {
        float s = wsum[0] + wsum[1] + wsum[2] + wsum[3];
        atomicAdd(out, s * (1.0f / NROWS));
    }
}

// ---------------------------------------------------------------- launch
extern "C" void kernel_launch(void* const* d_in, const int* in_sizes, int n_in,
                              void* d_out, int out_size, void* d_ws, size_t ws_size,
                              hipStream_t stream) {
    const float* q = (const float*)d_in[0];
    const float* c = (const float*)d_in[1];
    float* out = (float*)d_out;

    char* ws = (char*)d_ws;
    bf16* qn = (bf16*)ws;                                        // 12.6 MB
    bf16* cn = (bf16*)(ws + (size_t)NROWS * DDIM * 2);           // 12.6 MB
    float* diag = (float*)(ws + (size_t)NROWS * DDIM * 4);       // 32 KB
    float* partial = diag + NROWS;                               // 1 MB

    hipMemsetAsync(d_out, 0, sizeof(float), stream);

    norm_diag_kernel<<<NROWS / 4, 256, 0, stream>>>(q, c, qn, cn, diag);
    simgemm_kernel<<<256, 512, 0, stream>>>(qn, cn, partial);
    finalize_kernel<<<NROWS / 256, 256, 0, stream>>>(partial, diag, out);
}